// Round 5
// baseline (331.880 us; speedup 1.0000x reference)
//
#include <hip/hip_runtime.h>

typedef _Float16 f16;
typedef _Float16 h8_t __attribute__((ext_vector_type(8)));
typedef _Float16 h4_t __attribute__((ext_vector_type(4)));
typedef float f32x4 __attribute__((ext_vector_type(4)));
typedef float f32x16 __attribute__((ext_vector_type(16)));

#define BS 16
#define DA 512
#define SL 1024
#define NH 8
#define DH 64

// ---------------------------------------------------------------------------
// K1: BOTH projections in one launch (grid z = batch*2 + mode) so 1024 blocks
// fill the GPU at 4 blocks/CU (R4 ran 2x512-block launches at 2/CU, stall-
// bound). Fused transpose via LDS. Runtime mode select (uniform per block).
// mode 0 (k-proj): A=W (M=512), B=X^T (N=1024), out kp[b][s][o]
// mode 1 (v-proj): A=X^T (M=1024), B=W (N=512), out vp[b][o][s]
// ---------------------------------------------------------------------------
__global__ __launch_bounds__(256, 4) void fused_proj_both(
    const float* __restrict__ k_w, const float* __restrict__ v_w,
    const float* __restrict__ k_in, const float* __restrict__ v_in,
    const float* __restrict__ k_b, const float* __restrict__ v_b,
    f16* __restrict__ kp, f16* __restrict__ vp) {
  __shared__ f16 Wl[128 * 40];      // [o][c] f16
  __shared__ f16 Xl[128 * 40];      // [s][c] f16 (transposed)
  __shared__ float Xf32[32 * 132];  // [c][s] staging
  const int mode = blockIdx.z & 1;
  const int b = blockIdx.z >> 1;
  const int x = blockIdx.x;  // 0..31
  const int m0 = (mode ? (x >> 2) : (x & 3)) * 128;
  const int n0 = (mode ? (x & 3) : (x >> 2)) * 128;
  const float* Wg = mode ? v_w : k_w;
  const float* Xin = mode ? v_in : k_in;
  const float* bias = mode ? v_b : k_b;
  f16* outg = mode ? vp : kp;
  const int MT = mode ? SL : DA;
  const int NT = mode ? DA : SL;
  const int o_base = mode ? n0 : m0;
  const int s_base = mode ? m0 : n0;
  const int t = threadIdx.x;
  const int w = t >> 6, lane = t & 63, lr = lane & 15, lq = lane >> 4;
  const int wm = (w >> 1) * 64, wn = (w & 1) * 64;

  f32x4 acc[4][4] = {};

  for (int kt = 0; kt < 16; ++kt) {
    const int c0 = kt * 32;
    __syncthreads();  // prev iter's Xf32 + Wl/Xl MFMA reads done
    // stage W tile (128 o x 32 c, f32 -> f16)
#pragma unroll
    for (int p = 0; p < 4; ++p) {
      const int idx = p * 256 + t;
      const int row = idx >> 3, cq = (idx & 7) * 4;
      const float4 v = *(const float4*)&Wg[(size_t)(o_base + row) * DA + c0 + cq];
      h4_t hv;
      hv[0] = (f16)v.x; hv[1] = (f16)v.y; hv[2] = (f16)v.z; hv[3] = (f16)v.w;
      *(h4_t*)&Wl[row * 40 + cq] = hv;
    }
    // stage1: X f32 tile [32 c][128 s], coalesced along s
#pragma unroll
    for (int p = 0; p < 4; ++p) {
      const int idx = p * 256 + t;
      const int cc = idx >> 5, s4 = (idx & 31) * 4;
      const float4 v = *(const float4*)&Xin[((size_t)b * DA + c0 + cc) * SL + s_base + s4];
      *(float4*)&Xf32[cc * 132 + s4] = v;
    }
    __syncthreads();
    // stage2: transpose to Xl [s][c] f16
    {
      const int srow = t >> 1, cb = (t & 1) * 16;
      h8_t lo, hi;
#pragma unroll
      for (int u = 0; u < 8; ++u) lo[u] = (f16)Xf32[(cb + u) * 132 + srow];
#pragma unroll
      for (int u = 0; u < 8; ++u) hi[u] = (f16)Xf32[(cb + 8 + u) * 132 + srow];
      *(h8_t*)&Xl[srow * 40 + cb] = lo;
      *(h8_t*)&Xl[srow * 40 + cb + 8] = hi;
    }
    __syncthreads();
    const f16* Al = mode ? Xl : Wl;
    const f16* Bl = mode ? Wl : Xl;
    h8_t af[4], bf[4];
#pragma unroll
    for (int i = 0; i < 4; ++i) af[i] = *(const h8_t*)&Al[(wm + i * 16 + lr) * 40 + lq * 8];
#pragma unroll
    for (int j = 0; j < 4; ++j) bf[j] = *(const h8_t*)&Bl[(wn + j * 16 + lr) * 40 + lq * 8];
#pragma unroll
    for (int i = 0; i < 4; ++i)
#pragma unroll
      for (int j = 0; j < 4; ++j)
        acc[i][j] = __builtin_amdgcn_mfma_f32_16x16x32_f16(af[i], bf[j], acc[i][j], 0, 0, 0);
  }

  // epilogue: D row = gm (4 consecutive per lane -> 8B f16 stores), col = gn
#pragma unroll
  for (int i = 0; i < 4; ++i) {
    const int gmb = m0 + wm + i * 16 + lq * 4;
    float bm[4] = {0.f, 0.f, 0.f, 0.f};
    if (mode == 0) {
      const float4 b4 = *(const float4*)&bias[gmb];
      bm[0] = b4.x; bm[1] = b4.y; bm[2] = b4.z; bm[3] = b4.w;
    }
#pragma unroll
    for (int j = 0; j < 4; ++j) {
      const int gn = n0 + wn + j * 16 + lr;
      const float bn = mode ? bias[gn] : 0.f;
      h4_t hv;
#pragma unroll
      for (int r = 0; r < 4; ++r) {
        const float val = acc[i][j][r] + (mode ? bn : bm[r]);
        hv[r] = (f16)val;
      }
      *(h4_t*)&outg[((size_t)b * NT + gn) * MT + gmb] = hv;
    }
  }
}

// ---------------------------------------------------------------------------
// K2: fused flash attention, software-pipelined one j-tile ahead.
// grid (BS*NH, SL/256), block 256 (4 waves x 64 i). 32x32x16 MFMA,
// S^T = K*Q^T with sigma-permuted K rows (P feeds PV straight from regs).
// Per tile: barrier / stage K,V_{t+1} / barrier / S_{t+1} MFMA || softmax_t
// VALU || PV_t MFMA || prefetch_{t+2} VMEM  -- cross-tile ILP fills all pipes.
// sa ping-pong via unroll-2 (no copies).
// ---------------------------------------------------------------------------
__global__ __launch_bounds__(256, 2) void attn_kernel(
    const float* __restrict__ qg, const f16* __restrict__ kp, const f16* __restrict__ vp,
    const float* __restrict__ gamma, const float* __restrict__ gbns,
    const int* __restrict__ maskg, float* __restrict__ outg) {
  __shared__ __align__(16) char smem[36864];
  f16* KV = (f16*)smem;       // 2 bufs x (K[64][72] + V[64][72]) f16
  float* Osh = (float*)smem;  // epilogue overlay [32 d][256 i] f32

  const int bh = blockIdx.x, b = bh >> 3, h = bh & 7;
  const int i0 = blockIdx.y * 256;
  const int t = threadIdx.x, w = t >> 6, lane = t & 63;
  const int l5 = lane & 31, hf = lane >> 5;
  const float scale = gamma[h] / gbns[h] * 1.44269504088896f;  // GBN scale * log2(e)

  // ---- state (declared before lambdas; captured by reference)
  float m_i[2] = {-3e38f, -3e38f}, l_i[2] = {0.f, 0.f};
  f32x16 acc[2][2] = {};  // [im][nd]
  uint4 rk[2], rv[2];
  h8_t qf[2][4];

  // ---- Q fragments straight from global (B-operand: n=i, k=d)
#pragma unroll
  for (int im = 0; im < 2; ++im)
#pragma unroll
    for (int ks = 0; ks < 4; ++ks) {
      h8_t v;
#pragma unroll
      for (int u = 0; u < 8; ++u) {
        const int d = ks * 16 + hf * 8 + u;
        v[u] = (f16)(qg[((size_t)b * DA + h * DH + d) * SL + i0 + w * 64 + im * 32 + l5] * scale);
      }
      qf[im][ks] = v;
    }

  const int srow = t >> 3;  // 0..31
  const int c8 = (t & 7) * 8;
  const int row0 = srow, row1 = 32 + srow;
  const int rowp0 = (row0 & ~12) | ((row0 & 4) << 1) | ((row0 & 8) >> 1);
  const int rowp1 = (row1 & ~12) | ((row1 & 4) << 1) | ((row1 & 8) >> 1);

  auto gload = [&](int jn) {
    rk[0] = *(const uint4*)&kp[((size_t)b * SL + jn + row0) * DA + h * DH + c8];
    rv[0] = *(const uint4*)&vp[((size_t)b * DA + h * DH + row0) * SL + jn + c8];
    rk[1] = *(const uint4*)&kp[((size_t)b * SL + jn + row1) * DA + h * DH + c8];
    rv[1] = *(const uint4*)&vp[((size_t)b * DA + h * DH + row1) * SL + jn + c8];
  };
  auto swrite = [&](int bi) {
    f16* Kn = KV + bi * 9216;
    f16* Vn = Kn + 4608;
    *(uint4*)&Kn[rowp0 * 72 + c8] = rk[0];
    *(uint4*)&Vn[row0 * 72 + c8] = rv[0];
    *(uint4*)&Kn[rowp1 * 72 + c8] = rk[1];
    *(uint4*)&Vn[row1 * 72 + c8] = rv[1];
  };
  auto computeS = [&](f32x16 (&sa)[2][2], int bi) {
    const f16* Kc = KV + bi * 9216;
#pragma unroll
    for (int im = 0; im < 2; ++im)
#pragma unroll
      for (int mj = 0; mj < 2; ++mj) sa[im][mj] = (f32x16)(0.f);
#pragma unroll
    for (int ks = 0; ks < 4; ++ks)
#pragma unroll
      for (int mj = 0; mj < 2; ++mj) {
        const h8_t kf = *(const h8_t*)&Kc[(mj * 32 + l5) * 72 + ks * 16 + hf * 8];
#pragma unroll
        for (int im = 0; im < 2; ++im)
          sa[im][mj] = __builtin_amdgcn_mfma_f32_32x32x16_f16(kf, qf[im][ks], sa[im][mj], 0, 0, 0);
      }
  };
  auto softmax_pv = [&](f32x16 (&sa)[2][2], int jt, int bi) {
    const int j0 = jt * 64;
    const f16* Vc = KV + bi * 9216 + 4608;
    // key-mask quads, sigma-mapped: reg e=q*4+r <-> j = mj*32+16(q>>1)+8hf+4(q&1)+r
    int4 mq[2][4];
#pragma unroll
    for (int mj = 0; mj < 2; ++mj)
#pragma unroll
      for (int q = 0; q < 4; ++q)
        mq[mj][q] =
            *(const int4*)&maskg[b * SL + j0 + mj * 32 + (q >> 1) * 16 + hf * 8 + (q & 1) * 4];
#pragma unroll
    for (int mj = 0; mj < 2; ++mj)
#pragma unroll
      for (int q = 0; q < 4; ++q) {
        const int4 m4 = mq[mj][q];
#pragma unroll
        for (int im = 0; im < 2; ++im) {
          if (m4.x) sa[im][mj][q * 4 + 0] = -1e9f;
          if (m4.y) sa[im][mj][q * 4 + 1] = -1e9f;
          if (m4.z) sa[im][mj][q * 4 + 2] = -1e9f;
          if (m4.w) sa[im][mj][q * 4 + 3] = -1e9f;
        }
      }
    // online softmax, two independent chains; exp2 domain; per-lane i
    float alpha[2];
#pragma unroll
    for (int im = 0; im < 2; ++im) {
      float mx = sa[im][0][0];
#pragma unroll
      for (int e = 1; e < 16; ++e) mx = fmaxf(mx, sa[im][0][e]);
#pragma unroll
      for (int e = 0; e < 16; ++e) mx = fmaxf(mx, sa[im][1][e]);
      mx = fmaxf(mx, __shfl_xor(mx, 32));
      const float mn = fmaxf(m_i[im], mx);
      alpha[im] = __builtin_amdgcn_exp2f(m_i[im] - mn);
      m_i[im] = mn;
      float rs = 0.f;
#pragma unroll
      for (int mj = 0; mj < 2; ++mj)
#pragma unroll
        for (int e = 0; e < 16; ++e) {
          const float pv = __builtin_amdgcn_exp2f(sa[im][mj][e] - mn);
          sa[im][mj][e] = pv;
          rs += pv;
        }
      rs += __shfl_xor(rs, 32);
      l_i[im] = l_i[im] * alpha[im] + rs;
#pragma unroll
      for (int nd = 0; nd < 2; ++nd)
#pragma unroll
        for (int e = 0; e < 16; ++e) acc[im][nd][e] *= alpha[im];
    }
    // O^T += V^T * P^T : B = P straight from regs (sigma cancellation)
#pragma unroll
    for (int jk = 0; jk < 4; ++jk) {
      const int mj = jk >> 1, g = jk & 1;
      h8_t pf[2];
#pragma unroll
      for (int im = 0; im < 2; ++im) {
        h8_t pk;
#pragma unroll
        for (int u = 0; u < 8; ++u) pk[u] = (f16)sa[im][mj][g * 8 + u];
        pf[im] = pk;
      }
#pragma unroll
      for (int nd = 0; nd < 2; ++nd) {
        const h8_t vf = *(const h8_t*)&Vc[(nd * 32 + l5) * 72 + jk * 16 + hf * 8];
#pragma unroll
        for (int im = 0; im < 2; ++im)
          acc[im][nd] = __builtin_amdgcn_mfma_f32_32x32x16_f16(vf, pf[im], acc[im][nd], 0, 0, 0);
      }
    }
  };

  // ---- preamble: stage tile 0, prefetch tile 1, S_0
  gload(0);
  swrite(0);
  gload(64);
  __syncthreads();
  f32x16 saA[2][2], saB[2][2];
  computeS(saA, 0);

  // ---- pipelined main loop, unroll-2 ping-pong
  for (int tt = 0; tt < 8; ++tt) {
    const int ta = 2 * tt, tb = 2 * tt + 1;
    // tile ta (buf 0): S_{ta+1} into saB overlaps softmax/PV of saA
    __syncthreads();                    // all waves done with V_{ta-1} (buf 1)
    swrite(1);                          // K/V_{ta+1} -> buf 1
    __syncthreads();
    computeS(saB, 1);                   // S_{ta+1} (MFMA pipe)
    if (ta < 14) gload((ta + 2) * 64);  // K/V_{ta+2} (VMEM)
    softmax_pv(saA, ta, 0);             // softmax (VALU) + PV (MFMA)
    // tile tb (buf 1)
    __syncthreads();
    if (tb < 15) swrite(0);             // K/V_{tb+1} -> buf 0
    __syncthreads();
    if (tb < 15) computeS(saA, 0);      // S_{tb+1}
    if (tb < 14) gload((tb + 2) * 64);
    softmax_pv(saB, tb, 1);
  }

  // ---- epilogue: per-lane 1/l (0 for masked query rows), LDS bounce per nd
  float fac[2];
#pragma unroll
  for (int im = 0; im < 2; ++im) {
    const int mo = maskg[b * SL + i0 + w * 64 + im * 32 + l5];
    fac[im] = mo ? 0.f : 1.f / l_i[im];
  }
  __syncthreads();  // all waves done reading KV before Osh overlay

#pragma unroll
  for (int nd = 0; nd < 2; ++nd) {
#pragma unroll
    for (int im = 0; im < 2; ++im)
#pragma unroll
      for (int e = 0; e < 16; ++e) {
        const int dl = (e & 3) + 8 * (e >> 2) + 4 * hf;
        Osh[dl * 256 + w * 64 + im * 32 + l5] = acc[im][nd][e] * fac[im];
      }
    __syncthreads();
#pragma unroll
    for (int pass = 0; pass < 8; ++pass) {
      const int row = pass * 4 + w;
      const int i4 = lane * 4;
      const float4 o = *(const float4*)&Osh[row * 256 + i4];
      *(float4*)&outg[((size_t)b * DA + h * DH + nd * 32 + row) * SL + i0 + i4] = o;
    }
    __syncthreads();
  }
}

// ---------------------------------------------------------------------------
extern "C" void kernel_launch(void* const* d_in, const int* in_sizes, int n_in,
                              void* d_out, int out_size, void* d_ws, size_t ws_size,
                              hipStream_t stream) {
  const float* q     = (const float*)d_in[0];
  const float* k_in  = (const float*)d_in[1];
  const float* v_in  = (const float*)d_in[2];
  const float* k_w   = (const float*)d_in[3];
  const float* k_b   = (const float*)d_in[4];
  const float* v_w   = (const float*)d_in[5];
  const float* v_b   = (const float*)d_in[6];
  const float* gamma = (const float*)d_in[7];
  const float* gbns  = (const float*)d_in[10];  // gbn_bias/gbn_m cancel under softmax
  const int*   mask  = (const int*)d_in[11];
  float* out = (float*)d_out;

  const size_t NEL = (size_t)BS * SL * DA;
  f16* kpw = (f16*)d_ws;  // k projection, [b][s][o], 16 MiB
  f16* vpw = kpw + NEL;   // v projection, [b][o][s], 16 MiB

  fused_proj_both<<<dim3(32, 1, BS * 2), 256, 0, stream>>>(k_w, v_w, k_in, v_in, k_b, v_b,
                                                           kpw, vpw);
  attn_kernel<<<dim3(BS * NH, SL / 256), 256, 0, stream>>>(q, kpw, vpw, gamma, gbns, mask, out);
}